// Round 5
// baseline (1507.080 us; speedup 1.0000x reference)
//
#include <hip/hip_runtime.h>
#include <hip/hip_bf16.h>
#include <float.h>

#define DD 128
#define NEG_SLOPE 0.2f

typedef __attribute__((ext_vector_type(8))) short bf16x8;
typedef __attribute__((ext_vector_type(4))) float f32x4;

__device__ __forceinline__ float lrelu(float v) {
    return fmaxf(v, 0.0f) + NEG_SLOPE * fminf(v, 0.0f);
}

__device__ __forceinline__ unsigned short f2bf(float f) {
    unsigned u = __float_as_uint(f);
    u += 0x7fff + ((u >> 16) & 1);   // round-to-nearest-even
    return (unsigned short)(u >> 16);
}
__device__ __forceinline__ float bf2f(unsigned short h) {
    return __uint_as_float(((unsigned)h) << 16);
}

// ---------------- preprocessing ----------------

__global__ void k_hist(const int* __restrict__ dst, int E, int* __restrict__ cnt) {
    int i = blockIdx.x * blockDim.x + threadIdx.x;
    if (i < E) atomicAdd(&cnt[dst[i]], 1);
}

__global__ __launch_bounds__(1024) void k_scan(const int* __restrict__ cnt,
                                               int* __restrict__ row_ptr, int N) {
    __shared__ int sums[1024];
    int tid = threadIdx.x;
    int total = N + 1;
    int chunk = (total + 1023) / 1024;
    int lo = tid * chunk;
    int hi = min(lo + chunk, total);
    int s = 0;
    for (int i = lo; i < hi; ++i) s += (i < N) ? (cnt[i] + 1) : 0;
    sums[tid] = s;
    __syncthreads();
    for (int off = 1; off < 1024; off <<= 1) {
        int t = (tid >= off) ? sums[tid - off] : 0;
        __syncthreads();
        sums[tid] += t;
        __syncthreads();
    }
    int run = sums[tid] - s;
    for (int i = lo; i < hi; ++i) {
        row_ptr[i] = run;
        run += (i < N) ? (cnt[i] + 1) : 0;
    }
}

__global__ void k_scatter(const int* __restrict__ dst, int E, int N,
                          const int* __restrict__ row_ptr, int* __restrict__ fill,
                          const int* __restrict__ cnt, int* __restrict__ eids) {
    int i = blockIdx.x * blockDim.x + threadIdx.x;
    int tot = E + N;
    if (i >= tot) return;
    if (i < E) {
        int d = dst[i];
        int p = atomicAdd(&fill[d], 1);
        eids[row_ptr[d] + p] = i;
    } else {
        int n = i - E;
        eids[row_ptr[n] + cnt[n]] = E + n;
    }
}

// canonicalize row order (atomic scatter order varies per launch)
__global__ void k_sort_rows(const int* __restrict__ row_ptr, int* __restrict__ eids, int N) {
    int n = blockIdx.x * blockDim.x + threadIdx.x;
    if (n >= N) return;
    int s = row_ptr[n], e = row_ptr[n + 1];
    for (int i = s + 1; i < e; ++i) {
        int v = eids[i];
        int j = i - 1;
        while (j >= s && eids[j] > v) { eids[j + 1] = eids[j]; --j; }
        eids[j + 1] = v;
    }
}

// wave-per-node: loop_attr[n,:] = mean of incoming edge attrs (0 if none)
__global__ __launch_bounds__(256) void k_loop_attr(const float* __restrict__ ea,
                                                   const int* __restrict__ row_ptr,
                                                   const int* __restrict__ cnt,
                                                   const int* __restrict__ eids,
                                                   float* __restrict__ loop_attr, int N) {
    int wid = (blockIdx.x * blockDim.x + threadIdx.x) >> 6;
    int lane = threadIdx.x & 63;
    if (wid >= N) return;
    int s = row_ptr[wid];
    int c = cnt[wid];
    float2 acc = make_float2(0.f, 0.f);
    for (int c0 = 0; c0 < c; c0 += 64) {
        int m = min(64, c - c0);
        int eid = 0;
        if (lane < m) eid = eids[s + c0 + lane];
        for (int p = 0; p < m; ++p) {
            int e = __shfl(eid, p);
            float2 v = *reinterpret_cast<const float2*>(ea + (size_t)e * DD + 2 * lane);
            acc.x += v.x; acc.y += v.y;
        }
    }
    float inv = 1.0f / fmaxf((float)c, 1.0f);
    float2 o = make_float2(acc.x * inv, acc.y * inv);
    *reinterpret_cast<float2*>(loop_attr + (size_t)wid * DD + 2 * lane) = o;
}

// prepack W (per layer) into MFMA A-fragment order, bf16 hi/lo.
// WA[l][h][ks][g][j][i] = bf16_h( W[l][ks*32+g*8+i][j] ),  j=0..127, i=0..7
__global__ void k_prepack(const float* __restrict__ W, unsigned short* __restrict__ WA, int L) {
    int idx = blockIdx.x * blockDim.x + threadIdx.x;
    int total = L * DD * DD;
    if (idx >= total) return;
    int l = idx >> 14;
    int rem = idx & 16383;
    int k = rem >> 7;
    int j = rem & 127;
    float w = W[(size_t)l * 16384 + (size_t)k * DD + j];
    unsigned short h = f2bf(w);
    unsigned short lo = f2bf(w - bf2f(h));
    int ks = k >> 5, g = (k >> 3) & 3, i = k & 7;
    size_t off = ((size_t)(ks * 4 + g) * DD + j) * 8 + i;   // within half
    unsigned short* base = WA + (size_t)l * 32768;
    base[off] = h;
    base[16384 + off] = lo;
}

// ---------------- per-layer kernels ----------------

// MFMA node transform: Y[r,:] = X[r,:] @ W + b   (bf16x2 split, 3 products)
// wave = 32 rows x 128 features; block = 4 waves = 128 rows.
__global__ __launch_bounds__(256, 2) void k_gemm_mfma(
    const float* __restrict__ X, const unsigned short* __restrict__ WA,
    const float* __restrict__ b, float* __restrict__ Y, int N) {

    int tid  = threadIdx.x;
    int lane = tid & 63;
    int wv   = tid >> 6;
    int lc   = lane & 15;
    int g    = lane >> 4;

    int r0 = blockIdx.x * 128 + wv * 32;
    int rv[2]; bool ok[2];
    const float* rp[2];
    #pragma unroll
    for (int nf = 0; nf < 2; ++nf) {
        rv[nf] = r0 + nf * 16 + lc;
        ok[nf] = (rv[nf] < N);
        rp[nf] = X + (size_t)(ok[nf] ? rv[nf] : 0) * DD;
    }

    f32x4 acc[8][2];
    #pragma unroll
    for (int m = 0; m < 8; ++m)
        #pragma unroll
        for (int n = 0; n < 2; ++n)
            acc[m][n] = (f32x4){0.f, 0.f, 0.f, 0.f};

    float4 pr0[2], pr1[2];
    #pragma unroll
    for (int nf = 0; nf < 2; ++nf) {
        pr0[nf] = *reinterpret_cast<const float4*>(rp[nf] + g * 8);
        pr1[nf] = *reinterpret_cast<const float4*>(rp[nf] + g * 8 + 4);
    }

    #pragma unroll
    for (int ks = 0; ks < 4; ++ks) {
        bf16x8 Bh[2], Bl[2];
        #pragma unroll
        for (int nf = 0; nf < 2; ++nf) {
            float v[8] = {pr0[nf].x, pr0[nf].y, pr0[nf].z, pr0[nf].w,
                          pr1[nf].x, pr1[nf].y, pr1[nf].z, pr1[nf].w};
            #pragma unroll
            for (int i = 0; i < 8; ++i) {
                unsigned short h = f2bf(v[i]);
                Bh[nf][i] = (short)h;
                Bl[nf][i] = (short)f2bf(v[i] - bf2f(h));
            }
        }
        if (ks < 3) {
            int k0n = (ks + 1) * 32 + g * 8;
            #pragma unroll
            for (int nf = 0; nf < 2; ++nf) {
                pr0[nf] = *reinterpret_cast<const float4*>(rp[nf] + k0n);
                pr1[nf] = *reinterpret_cast<const float4*>(rp[nf] + k0n + 4);
            }
        }
        #pragma unroll
        for (int mf = 0; mf < 8; ++mf) {
            size_t aoff = ((size_t)(ks * 4 + g) * DD + (mf * 16 + lc)) * 8;
            bf16x8 Ah = *reinterpret_cast<const bf16x8*>(WA + aoff);
            bf16x8 Al = *reinterpret_cast<const bf16x8*>(WA + 16384 + aoff);
            #pragma unroll
            for (int nf = 0; nf < 2; ++nf) {
                acc[mf][nf] = __builtin_amdgcn_mfma_f32_16x16x32_bf16(Ah, Bh[nf], acc[mf][nf], 0, 0, 0);
                acc[mf][nf] = __builtin_amdgcn_mfma_f32_16x16x32_bf16(Al, Bh[nf], acc[mf][nf], 0, 0, 0);
                acc[mf][nf] = __builtin_amdgcn_mfma_f32_16x16x32_bf16(Ah, Bl[nf], acc[mf][nf], 0, 0, 0);
            }
        }
    }

    #pragma unroll
    for (int mf = 0; mf < 8; ++mf) {
        int f0 = mf * 16 + g * 4;
        float4 bv = *reinterpret_cast<const float4*>(b + f0);
        #pragma unroll
        for (int nf = 0; nf < 2; ++nf) {
            if (!ok[nf]) continue;
            float4 o;
            o.x = acc[mf][nf][0] + bv.x;
            o.y = acc[mf][nf][1] + bv.y;
            o.z = acc[mf][nf][2] + bv.z;
            o.w = acc[mf][nf][3] + bv.w;
            *reinterpret_cast<float4*>(Y + (size_t)rv[nf] * DD + f0) = o;
        }
    }
}

// MFMA edge-logits: D[j][e] = sum_k We[k][j]*ea[e][k]  (bf16x2 split, 3 products)
// wave = 32 edges x 128 features; block = 4 waves = 128 edges. B prefetched 1 ks ahead.
__global__ __launch_bounds__(256, 2) void k_edge_mfma(
    const float* __restrict__ ea, const float* __restrict__ loop_attr,
    const int* __restrict__ srcArr, const int* __restrict__ dstArr,
    const unsigned short* __restrict__ WA, const float* __restrict__ att,
    const float* __restrict__ xl, const float* __restrict__ xr,
    float* __restrict__ logits, int E, int Etot) {

    int tid  = threadIdx.x;
    int lane = tid & 63;
    int wv   = tid >> 6;
    int lc   = lane & 15;
    int g    = lane >> 4;

    int e0 = blockIdx.x * 128 + wv * 32;

    const float* rp[2];
    int   sn[2], dn[2], ev[2];
    bool  ok[2];
    #pragma unroll
    for (int nf = 0; nf < 2; ++nf) {
        int e = e0 + nf * 16 + lc;
        ev[nf] = e;
        ok[nf] = (e < Etot);
        if (e < E)            { rp[nf] = ea + (size_t)e * DD; sn[nf] = srcArr[e]; dn[nf] = dstArr[e]; }
        else if (e < Etot)    { rp[nf] = loop_attr + (size_t)(e - E) * DD; sn[nf] = e - E; dn[nf] = e - E; }
        else                  { rp[nf] = ea; sn[nf] = 0; dn[nf] = 0; }
    }

    f32x4 acc[8][2];
    #pragma unroll
    for (int m = 0; m < 8; ++m)
        #pragma unroll
        for (int n = 0; n < 2; ++n)
            acc[m][n] = (f32x4){0.f, 0.f, 0.f, 0.f};

    float4 pr0[2], pr1[2];
    #pragma unroll
    for (int nf = 0; nf < 2; ++nf) {
        pr0[nf] = *reinterpret_cast<const float4*>(rp[nf] + g * 8);
        pr1[nf] = *reinterpret_cast<const float4*>(rp[nf] + g * 8 + 4);
    }

    #pragma unroll
    for (int ks = 0; ks < 4; ++ks) {
        bf16x8 Bh[2], Bl[2];
        #pragma unroll
        for (int nf = 0; nf < 2; ++nf) {
            float v[8] = {pr0[nf].x, pr0[nf].y, pr0[nf].z, pr0[nf].w,
                          pr1[nf].x, pr1[nf].y, pr1[nf].z, pr1[nf].w};
            #pragma unroll
            for (int i = 0; i < 8; ++i) {
                unsigned short h = f2bf(v[i]);
                Bh[nf][i] = (short)h;
                Bl[nf][i] = (short)f2bf(v[i] - bf2f(h));
            }
        }
        if (ks < 3) {
            int k0n = (ks + 1) * 32 + g * 8;
            #pragma unroll
            for (int nf = 0; nf < 2; ++nf) {
                pr0[nf] = *reinterpret_cast<const float4*>(rp[nf] + k0n);
                pr1[nf] = *reinterpret_cast<const float4*>(rp[nf] + k0n + 4);
            }
        }
        #pragma unroll
        for (int mf = 0; mf < 8; ++mf) {
            size_t aoff = ((size_t)(ks * 4 + g) * DD + (mf * 16 + lc)) * 8;
            bf16x8 Ah = *reinterpret_cast<const bf16x8*>(WA + aoff);
            bf16x8 Al = *reinterpret_cast<const bf16x8*>(WA + 16384 + aoff);
            #pragma unroll
            for (int nf = 0; nf < 2; ++nf) {
                acc[mf][nf] = __builtin_amdgcn_mfma_f32_16x16x32_bf16(Ah, Bh[nf], acc[mf][nf], 0, 0, 0);
                acc[mf][nf] = __builtin_amdgcn_mfma_f32_16x16x32_bf16(Al, Bh[nf], acc[mf][nf], 0, 0, 0);
                acc[mf][nf] = __builtin_amdgcn_mfma_f32_16x16x32_bf16(Ah, Bl[nf], acc[mf][nf], 0, 0, 0);
            }
        }
    }

    // epilogue: per acc reg r, feature f = mf*16 + g*4 + r; edge = ev[nf]
    float partial[2] = {0.f, 0.f};
    #pragma unroll
    for (int mf = 0; mf < 8; ++mf) {
        int f0 = mf * 16 + g * 4;
        float4 attv = *reinterpret_cast<const float4*>(att + f0);
        #pragma unroll
        for (int nf = 0; nf < 2; ++nf) {
            float4 xlv = *reinterpret_cast<const float4*>(xl + (size_t)sn[nf] * DD + f0);
            float4 xrv = *reinterpret_cast<const float4*>(xr + (size_t)dn[nf] * DD + f0);
            float t0 = acc[mf][nf][0] + xlv.x + xrv.x;
            float t1 = acc[mf][nf][1] + xlv.y + xrv.y;
            float t2 = acc[mf][nf][2] + xlv.z + xrv.z;
            float t3 = acc[mf][nf][3] + xlv.w + xrv.w;
            partial[nf] += attv.x * lrelu(t0) + attv.y * lrelu(t1)
                         + attv.z * lrelu(t2) + attv.w * lrelu(t3);
        }
    }
    #pragma unroll
    for (int nf = 0; nf < 2; ++nf) {
        float p = partial[nf];
        p += __shfl_xor(p, 16);
        p += __shfl_xor(p, 32);
        if (lane < 16 && ok[nf]) logits[ev[nf]] = p;
    }
}

// thread-per-node: logits -> unnormalized weights (in place) + per-node denominator
__global__ void k_softmax(float* __restrict__ logits, const int* __restrict__ row_ptr,
                          const int* __restrict__ eids, float* __restrict__ den, int N) {
    int i = blockIdx.x * blockDim.x + threadIdx.x;
    if (i >= N) return;
    int s = row_ptr[i], e = row_ptr[i + 1];
    float mx = -FLT_MAX;
    for (int p = s; p < e; ++p) mx = fmaxf(mx, logits[eids[p]]);
    float d = 0.f;
    for (int p = s; p < e; ++p) {
        int id = eids[p];
        float w = __expf(logits[id] - mx);
        logits[id] = w;
        d += w;
    }
    den[i] = d;
}

// wave-per-node aggregation: out[n,:] = (sum_e w[e]*xl[src[e],:]) / den[n] + bias
__global__ __launch_bounds__(256) void k_agg(
    const float* __restrict__ w, const float* __restrict__ den,
    const int* __restrict__ row_ptr, const int* __restrict__ eids,
    const int* __restrict__ srcArr, const float* __restrict__ xl,
    const float* __restrict__ bias, float* __restrict__ xout, int N, int E) {
    int wid = (blockIdx.x * blockDim.x + threadIdx.x) >> 6;
    int lane = threadIdx.x & 63;
    if (wid >= N) return;
    int s = row_ptr[wid], e = row_ptr[wid + 1];
    float2 acc = make_float2(0.f, 0.f);
    for (int c0 = s; c0 < e; c0 += 64) {
        int m = min(64, e - c0);
        float wv = 0.f; int sv = 0;
        if (lane < m) {
            int eid = eids[c0 + lane];
            wv = w[eid];
            sv = (eid < E) ? srcArr[eid] : (eid - E);
        }
        for (int p = 0; p < m; ++p) {
            float wp = __shfl(wv, p);
            int   rw = __shfl(sv, p);
            float2 v = *reinterpret_cast<const float2*>(xl + (size_t)rw * DD + 2 * lane);
            acc.x += wp * v.x;
            acc.y += wp * v.y;
        }
    }
    float inv = 1.0f / den[wid];
    float2 bv = *reinterpret_cast<const float2*>(bias + 2 * lane);
    float2 o = make_float2(acc.x * inv + bv.x, acc.y * inv + bv.y);
    *reinterpret_cast<float2*>(xout + (size_t)wid * DD + 2 * lane) = o;
}

// ---------------- final score + top-k ----------------

__global__ __launch_bounds__(256) void k_scores(const float* __restrict__ X,
                                                const float* __restrict__ Wf,
                                                const float* __restrict__ bf,
                                                float* __restrict__ scores, int N) {
    int gid = blockIdx.x * blockDim.x + threadIdx.x;
    int node = gid >> 6;
    int lane = threadIdx.x & 63;
    if (node >= N) return;
    float2 xv = *reinterpret_cast<const float2*>(&X[(size_t)node * DD + lane * 2]);
    float2 wv = *reinterpret_cast<const float2*>(&Wf[lane * 2]);
    float p = xv.x * wv.x + xv.y * wv.y;
    p += __shfl_xor(p, 32);
    p += __shfl_xor(p, 16);
    p += __shfl_xor(p, 8);
    p += __shfl_xor(p, 4);
    p += __shfl_xor(p, 2);
    p += __shfl_xor(p, 1);
    if (lane == 0) scores[node] = p + bf[0];
}

__device__ __forceinline__ bool tk_better(float a, int ai, float b, int bi) {
    return (a > b) || (a == b && ai < bi);
}

__global__ __launch_bounds__(1024) void k_topk(const float* __restrict__ scores, int N,
                                               float* __restrict__ out) {
    __shared__ float lv[1024 * 10];
    __shared__ int li[1024 * 10];
    int t = threadIdx.x;
    float v[10]; int ix[10];
    #pragma unroll
    for (int j = 0; j < 10; ++j) { v[j] = -FLT_MAX; ix[j] = 0x7fffffff; }
    for (int i = t; i < N; i += 1024) {
        float sv = scores[i];
        if (tk_better(sv, i, v[9], ix[9])) {
            v[9] = sv; ix[9] = i;
            #pragma unroll
            for (int j = 9; j > 0; --j) {
                if (tk_better(v[j], ix[j], v[j - 1], ix[j - 1])) {
                    float tv = v[j]; v[j] = v[j - 1]; v[j - 1] = tv;
                    int ti = ix[j]; ix[j] = ix[j - 1]; ix[j - 1] = ti;
                }
            }
        }
    }
    #pragma unroll
    for (int j = 0; j < 10; ++j) { lv[t * 10 + j] = v[j]; li[t * 10 + j] = ix[j]; }
    __syncthreads();
    for (int sh = 512; sh >= 1; sh >>= 1) {
        if (t < sh) {
            float bv[10]; int bi[10];
            #pragma unroll
            for (int j = 0; j < 10; ++j) { bv[j] = lv[(t + sh) * 10 + j]; bi[j] = li[(t + sh) * 10 + j]; }
            float mv[10]; int mi[10];
            int i1 = 0, i2 = 0;
            #pragma unroll
            for (int k = 0; k < 10; ++k) {
                if (tk_better(v[i1], ix[i1], bv[i2], bi[i2])) { mv[k] = v[i1]; mi[k] = ix[i1]; ++i1; }
                else { mv[k] = bv[i2]; mi[k] = bi[i2]; ++i2; }
            }
            #pragma unroll
            for (int j = 0; j < 10; ++j) {
                v[j] = mv[j]; ix[j] = mi[j];
                lv[t * 10 + j] = v[j]; li[t * 10 + j] = ix[j];
            }
        }
        __syncthreads();
    }
    if (t == 0) {
        #pragma unroll
        for (int j = 0; j < 10; ++j) {
            out[j] = v[j];
            out[10 + j] = (float)ix[j];
        }
    }
}

// ---------------- host launch ----------------

static inline size_t alignup(size_t v) { return (v + 255) & ~(size_t)255; }

extern "C" void kernel_launch(void* const* d_in, const int* in_sizes, int n_in,
                              void* d_out, int out_size, void* d_ws, size_t ws_size,
                              hipStream_t stream) {
    const float* x    = (const float*)d_in[0];
    const int*   ei   = (const int*)d_in[1];
    const float* ea   = (const float*)d_in[2];
    const float* Wl   = (const float*)d_in[3];
    const float* bl   = (const float*)d_in[4];
    const float* Wr   = (const float*)d_in[5];
    const float* br   = (const float*)d_in[6];
    const float* We   = (const float*)d_in[7];
    const float* att  = (const float*)d_in[8];
    const float* bias = (const float*)d_in[9];
    const float* Wf   = (const float*)d_in[10];
    const float* bf   = (const float*)d_in[11];

    int N = in_sizes[0] / DD;
    int E = in_sizes[1] / 2;
    int L = in_sizes[3] / (DD * DD);
    int Etot = E + N;
    const int* src = ei;
    const int* dst = ei + E;

    size_t off = 0;
    char* wsb = (char*)d_ws;
    auto carve = [&](size_t bytes) -> void* { void* p = wsb + off; off += alignup(bytes); return p; };
    unsigned short* WAe = (unsigned short*)carve((size_t)L * 32768 * 2);
    unsigned short* WAl = (unsigned short*)carve((size_t)L * 32768 * 2);
    unsigned short* WAr = (unsigned short*)carve((size_t)L * 32768 * 2);
    int*   cnt       = (int*)carve((size_t)N * 4);
    int*   fill      = (int*)carve((size_t)N * 4);
    int*   row_ptr   = (int*)carve((size_t)(N + 1) * 4);
    int*   eids      = (int*)carve((size_t)Etot * 4);
    float* logits    = (float*)carve((size_t)Etot * 4);
    float* denBuf    = (float*)carve((size_t)N * 4);
    float* loop_attr = (float*)carve((size_t)N * DD * 4);
    float* xl        = (float*)carve((size_t)N * DD * 4);
    float* xr        = (float*)carve((size_t)N * DD * 4);
    float* xa        = (float*)carve((size_t)N * DD * 4);
    float* xb        = (float*)carve((size_t)N * DD * 4);
    float* scoresBuf = (float*)carve((size_t)N * 4);
    (void)ws_size; (void)n_in; (void)out_size;

    hipMemsetAsync(cnt, 0, (size_t)N * 4, stream);
    hipMemsetAsync(fill, 0, (size_t)N * 4, stream);

    int ppBlocks = (L * DD * DD + 255) / 256;
    k_prepack<<<ppBlocks, 256, 0, stream>>>(We, WAe, L);
    k_prepack<<<ppBlocks, 256, 0, stream>>>(Wl, WAl, L);
    k_prepack<<<ppBlocks, 256, 0, stream>>>(Wr, WAr, L);
    k_hist<<<(E + 255) / 256, 256, 0, stream>>>(dst, E, cnt);
    k_scan<<<1, 1024, 0, stream>>>(cnt, row_ptr, N);
    k_scatter<<<(Etot + 255) / 256, 256, 0, stream>>>(dst, E, N, row_ptr, fill, cnt, eids);
    k_sort_rows<<<(N + 255) / 256, 256, 0, stream>>>(row_ptr, eids, N);
    int waveBlocks = (N * 64 + 255) / 256;
    k_loop_attr<<<waveBlocks, 256, 0, stream>>>(ea, row_ptr, cnt, eids, loop_attr, N);

    const float* xin = x;
    float* xout = xa;
    int gemmBlocks = (N + 127) / 128;
    int edgeBlocks = (Etot + 127) / 128;
    for (int l = 0; l < L; ++l) {
        k_gemm_mfma<<<gemmBlocks, 256, 0, stream>>>(xin, WAl + (size_t)l * 32768, bl + (size_t)l * DD, xl, N);
        k_gemm_mfma<<<gemmBlocks, 256, 0, stream>>>(xin, WAr + (size_t)l * 32768, br + (size_t)l * DD, xr, N);
        k_edge_mfma<<<edgeBlocks, 256, 0, stream>>>(ea, loop_attr, src, dst,
                                                    WAe + (size_t)l * 32768, att + (size_t)l * DD,
                                                    xl, xr, logits, E, Etot);
        k_softmax<<<(N + 255) / 256, 256, 0, stream>>>(logits, row_ptr, eids, denBuf, N);
        k_agg<<<waveBlocks, 256, 0, stream>>>(logits, denBuf, row_ptr, eids, src, xl,
                                              bias + (size_t)l * DD, xout, N, E);
        xin = xout;
        xout = (xout == xa) ? xb : xa;
    }
    k_scores<<<(N + 3) / 4, 256, 0, stream>>>(xin, Wf, bf, scoresBuf, N);
    k_topk<<<1, 1024, 0, stream>>>(scoresBuf, N, (float*)d_out);
}

// Round 6
// 1494.792 us; speedup vs baseline: 1.0082x; 1.0082x over previous
//
#include <hip/hip_runtime.h>
#include <hip/hip_bf16.h>
#include <float.h>

#define DD 128
#define NEG_SLOPE 0.2f

typedef __attribute__((ext_vector_type(8))) short bf16x8;
typedef __attribute__((ext_vector_type(4))) float f32x4;

__device__ __forceinline__ float lrelu(float v) {
    return fmaxf(v, 0.0f) + NEG_SLOPE * fminf(v, 0.0f);
}

__device__ __forceinline__ unsigned short f2bf(float f) {
    unsigned u = __float_as_uint(f);
    u += 0x7fff + ((u >> 16) & 1);   // round-to-nearest-even
    return (unsigned short)(u >> 16);
}
__device__ __forceinline__ float bf2f(unsigned short h) {
    return __uint_as_float(((unsigned)h) << 16);
}

// ---------------- preprocessing ----------------

__global__ void k_hist(const int* __restrict__ dst, int E, int* __restrict__ cnt) {
    int i = blockIdx.x * blockDim.x + threadIdx.x;
    if (i < E) atomicAdd(&cnt[dst[i]], 1);
}

__global__ __launch_bounds__(1024) void k_scan(const int* __restrict__ cnt,
                                               int* __restrict__ row_ptr, int N) {
    __shared__ int sums[1024];
    int tid = threadIdx.x;
    int total = N + 1;
    int chunk = (total + 1023) / 1024;
    int lo = tid * chunk;
    int hi = min(lo + chunk, total);
    int s = 0;
    for (int i = lo; i < hi; ++i) s += (i < N) ? (cnt[i] + 1) : 0;
    sums[tid] = s;
    __syncthreads();
    for (int off = 1; off < 1024; off <<= 1) {
        int t = (tid >= off) ? sums[tid - off] : 0;
        __syncthreads();
        sums[tid] += t;
        __syncthreads();
    }
    int run = sums[tid] - s;
    for (int i = lo; i < hi; ++i) {
        row_ptr[i] = run;
        run += (i < N) ? (cnt[i] + 1) : 0;
    }
}

__global__ void k_scatter(const int* __restrict__ dst, int E, int N,
                          const int* __restrict__ row_ptr, int* __restrict__ fill,
                          const int* __restrict__ cnt, int* __restrict__ eids) {
    int i = blockIdx.x * blockDim.x + threadIdx.x;
    int tot = E + N;
    if (i >= tot) return;
    if (i < E) {
        int d = dst[i];
        int p = atomicAdd(&fill[d], 1);
        eids[row_ptr[d] + p] = i;
    } else {
        int n = i - E;
        eids[row_ptr[n] + cnt[n]] = E + n;
    }
}

// canonicalize row order (atomic scatter order varies per launch)
__global__ void k_sort_rows(const int* __restrict__ row_ptr, int* __restrict__ eids, int N) {
    int n = blockIdx.x * blockDim.x + threadIdx.x;
    if (n >= N) return;
    int s = row_ptr[n], e = row_ptr[n + 1];
    for (int i = s + 1; i < e; ++i) {
        int v = eids[i];
        int j = i - 1;
        while (j >= s && eids[j] > v) { eids[j + 1] = eids[j]; --j; }
        eids[j + 1] = v;
    }
}

// wave-per-node: loop_attr[n,:] = mean of incoming edge attrs (0 if none)
// edge loop unrolled x4 for memory-level parallelism
__global__ __launch_bounds__(256) void k_loop_attr(const float* __restrict__ ea,
                                                   const int* __restrict__ row_ptr,
                                                   const int* __restrict__ cnt,
                                                   const int* __restrict__ eids,
                                                   float* __restrict__ loop_attr, int N) {
    int wid = (blockIdx.x * blockDim.x + threadIdx.x) >> 6;
    int lane = threadIdx.x & 63;
    if (wid >= N) return;
    int s = row_ptr[wid];
    int c = cnt[wid];
    float2 acc = make_float2(0.f, 0.f);
    for (int c0 = 0; c0 < c; c0 += 64) {
        int m = min(64, c - c0);
        int eid = 0;
        if (lane < m) eid = eids[s + c0 + lane];
        int p = 0;
        for (; p + 4 <= m; p += 4) {
            int e0 = __shfl(eid, p), e1 = __shfl(eid, p + 1);
            int e2 = __shfl(eid, p + 2), e3 = __shfl(eid, p + 3);
            float2 v0 = *reinterpret_cast<const float2*>(ea + (size_t)e0 * DD + 2 * lane);
            float2 v1 = *reinterpret_cast<const float2*>(ea + (size_t)e1 * DD + 2 * lane);
            float2 v2 = *reinterpret_cast<const float2*>(ea + (size_t)e2 * DD + 2 * lane);
            float2 v3 = *reinterpret_cast<const float2*>(ea + (size_t)e3 * DD + 2 * lane);
            acc.x += v0.x; acc.y += v0.y;
            acc.x += v1.x; acc.y += v1.y;
            acc.x += v2.x; acc.y += v2.y;
            acc.x += v3.x; acc.y += v3.y;
        }
        for (; p < m; ++p) {
            int e = __shfl(eid, p);
            float2 v = *reinterpret_cast<const float2*>(ea + (size_t)e * DD + 2 * lane);
            acc.x += v.x; acc.y += v.y;
        }
    }
    float inv = 1.0f / fmaxf((float)c, 1.0f);
    float2 o = make_float2(acc.x * inv, acc.y * inv);
    *reinterpret_cast<float2*>(loop_attr + (size_t)wid * DD + 2 * lane) = o;
}

// prepack W (per layer) into MFMA A-fragment order, bf16 hi/lo.
// WA[l][h][ks][g][j][i] = bf16_h( W[l][ks*32+g*8+i][j] ),  j=0..127, i=0..7
__global__ void k_prepack(const float* __restrict__ W, unsigned short* __restrict__ WA, int L) {
    int idx = blockIdx.x * blockDim.x + threadIdx.x;
    int total = L * DD * DD;
    if (idx >= total) return;
    int l = idx >> 14;
    int rem = idx & 16383;
    int k = rem >> 7;
    int j = rem & 127;
    float w = W[(size_t)l * 16384 + (size_t)k * DD + j];
    unsigned short h = f2bf(w);
    unsigned short lo = f2bf(w - bf2f(h));
    int ks = k >> 5, g = (k >> 3) & 3, i = k & 7;
    size_t off = ((size_t)(ks * 4 + g) * DD + j) * 8 + i;   // within half
    unsigned short* base = WA + (size_t)l * 32768;
    base[off] = h;
    base[16384 + off] = lo;
}

// ---------------- per-layer kernels ----------------

// MFMA node transform: Y[r,:] = X[r,:] @ W + b   (bf16x2 split, 3 products)
// wave = 16 rows x 128 features (acc[8]=32 AGPR); block = 4 waves = 64 rows.
__global__ __launch_bounds__(256, 4) void k_gemm_mfma(
    const float* __restrict__ X, const unsigned short* __restrict__ WA,
    const float* __restrict__ b, float* __restrict__ Y, int N) {

    int tid  = threadIdx.x;
    int lane = tid & 63;
    int wv   = tid >> 6;
    int lc   = lane & 15;
    int g    = lane >> 4;

    int r = blockIdx.x * 64 + wv * 16 + lc;
    bool ok = (r < N);
    const float* rp = X + (size_t)(ok ? r : 0) * DD;

    f32x4 acc[8];
    #pragma unroll
    for (int m = 0; m < 8; ++m) acc[m] = (f32x4){0.f, 0.f, 0.f, 0.f};

    float4 pr0 = *reinterpret_cast<const float4*>(rp + g * 8);
    float4 pr1 = *reinterpret_cast<const float4*>(rp + g * 8 + 4);

    #pragma unroll
    for (int ks = 0; ks < 4; ++ks) {
        float v[8] = {pr0.x, pr0.y, pr0.z, pr0.w, pr1.x, pr1.y, pr1.z, pr1.w};
        bf16x8 Bh, Bl;
        #pragma unroll
        for (int i = 0; i < 8; ++i) {
            unsigned short h = f2bf(v[i]);
            Bh[i] = (short)h;
            Bl[i] = (short)f2bf(v[i] - bf2f(h));
        }
        if (ks < 3) {
            int k0n = (ks + 1) * 32 + g * 8;
            pr0 = *reinterpret_cast<const float4*>(rp + k0n);
            pr1 = *reinterpret_cast<const float4*>(rp + k0n + 4);
        }
        #pragma unroll
        for (int mf = 0; mf < 8; ++mf) {
            size_t aoff = ((size_t)(ks * 4 + g) * DD + (mf * 16 + lc)) * 8;
            bf16x8 Ah = *reinterpret_cast<const bf16x8*>(WA + aoff);
            bf16x8 Al = *reinterpret_cast<const bf16x8*>(WA + 16384 + aoff);
            acc[mf] = __builtin_amdgcn_mfma_f32_16x16x32_bf16(Ah, Bh, acc[mf], 0, 0, 0);
            acc[mf] = __builtin_amdgcn_mfma_f32_16x16x32_bf16(Al, Bh, acc[mf], 0, 0, 0);
            acc[mf] = __builtin_amdgcn_mfma_f32_16x16x32_bf16(Ah, Bl, acc[mf], 0, 0, 0);
        }
    }

    if (ok) {
        #pragma unroll
        for (int mf = 0; mf < 8; ++mf) {
            int f0 = mf * 16 + g * 4;
            float4 bv = *reinterpret_cast<const float4*>(b + f0);
            float4 o;
            o.x = acc[mf][0] + bv.x;
            o.y = acc[mf][1] + bv.y;
            o.z = acc[mf][2] + bv.z;
            o.w = acc[mf][3] + bv.w;
            *reinterpret_cast<float4*>(Y + (size_t)r * DD + f0) = o;
        }
    }
}

// MFMA edge-logits: D[j][e] = sum_k We[k][j]*ea[e][k]  (bf16x2 split, 3 products)
// wave = 16 edges x 128 features (acc[8]=32 AGPR); block = 4 waves = 64 edges.
__global__ __launch_bounds__(256, 4) void k_edge_mfma(
    const float* __restrict__ ea, const float* __restrict__ loop_attr,
    const int* __restrict__ srcArr, const int* __restrict__ dstArr,
    const unsigned short* __restrict__ WA, const float* __restrict__ att,
    const float* __restrict__ xl, const float* __restrict__ xr,
    float* __restrict__ logits, int E, int Etot) {

    int tid  = threadIdx.x;
    int lane = tid & 63;
    int wv   = tid >> 6;
    int lc   = lane & 15;
    int g    = lane >> 4;

    int e = blockIdx.x * 64 + wv * 16 + lc;
    bool ok = (e < Etot);
    const float* rp;
    int sn, dn;
    if (e < E)       { rp = ea + (size_t)e * DD; sn = srcArr[e]; dn = dstArr[e]; }
    else if (ok)     { rp = loop_attr + (size_t)(e - E) * DD; sn = e - E; dn = e - E; }
    else             { rp = ea; sn = 0; dn = 0; }

    f32x4 acc[8];
    #pragma unroll
    for (int m = 0; m < 8; ++m) acc[m] = (f32x4){0.f, 0.f, 0.f, 0.f};

    float4 pr0 = *reinterpret_cast<const float4*>(rp + g * 8);
    float4 pr1 = *reinterpret_cast<const float4*>(rp + g * 8 + 4);

    #pragma unroll
    for (int ks = 0; ks < 4; ++ks) {
        float v[8] = {pr0.x, pr0.y, pr0.z, pr0.w, pr1.x, pr1.y, pr1.z, pr1.w};
        bf16x8 Bh, Bl;
        #pragma unroll
        for (int i = 0; i < 8; ++i) {
            unsigned short h = f2bf(v[i]);
            Bh[i] = (short)h;
            Bl[i] = (short)f2bf(v[i] - bf2f(h));
        }
        if (ks < 3) {
            int k0n = (ks + 1) * 32 + g * 8;
            pr0 = *reinterpret_cast<const float4*>(rp + k0n);
            pr1 = *reinterpret_cast<const float4*>(rp + k0n + 4);
        }
        #pragma unroll
        for (int mf = 0; mf < 8; ++mf) {
            size_t aoff = ((size_t)(ks * 4 + g) * DD + (mf * 16 + lc)) * 8;
            bf16x8 Ah = *reinterpret_cast<const bf16x8*>(WA + aoff);
            bf16x8 Al = *reinterpret_cast<const bf16x8*>(WA + 16384 + aoff);
            acc[mf] = __builtin_amdgcn_mfma_f32_16x16x32_bf16(Ah, Bh, acc[mf], 0, 0, 0);
            acc[mf] = __builtin_amdgcn_mfma_f32_16x16x32_bf16(Al, Bh, acc[mf], 0, 0, 0);
            acc[mf] = __builtin_amdgcn_mfma_f32_16x16x32_bf16(Ah, Bl, acc[mf], 0, 0, 0);
        }
    }

    // epilogue: per acc reg r, feature f = mf*16 + g*4 + r
    float partial = 0.f;
    #pragma unroll
    for (int mf = 0; mf < 8; ++mf) {
        int f0 = mf * 16 + g * 4;
        float4 attv = *reinterpret_cast<const float4*>(att + f0);
        float4 xlv  = *reinterpret_cast<const float4*>(xl + (size_t)sn * DD + f0);
        float4 xrv  = *reinterpret_cast<const float4*>(xr + (size_t)dn * DD + f0);
        float t0 = acc[mf][0] + xlv.x + xrv.x;
        float t1 = acc[mf][1] + xlv.y + xrv.y;
        float t2 = acc[mf][2] + xlv.z + xrv.z;
        float t3 = acc[mf][3] + xlv.w + xrv.w;
        partial += attv.x * lrelu(t0) + attv.y * lrelu(t1)
                 + attv.z * lrelu(t2) + attv.w * lrelu(t3);
    }
    partial += __shfl_xor(partial, 16);
    partial += __shfl_xor(partial, 32);
    if (lane < 16 && ok) logits[e] = partial;
}

// thread-per-node: logits -> unnormalized weights (in place) + per-node denominator
__global__ void k_softmax(float* __restrict__ logits, const int* __restrict__ row_ptr,
                          const int* __restrict__ eids, float* __restrict__ den, int N) {
    int i = blockIdx.x * blockDim.x + threadIdx.x;
    if (i >= N) return;
    int s = row_ptr[i], e = row_ptr[i + 1];
    float mx = -FLT_MAX;
    for (int p = s; p < e; ++p) mx = fmaxf(mx, logits[eids[p]]);
    float d = 0.f;
    for (int p = s; p < e; ++p) {
        int id = eids[p];
        float w = __expf(logits[id] - mx);
        logits[id] = w;
        d += w;
    }
    den[i] = d;
}

// wave-per-node aggregation: out[n,:] = (sum_e w[e]*xl[src[e],:]) / den[n] + bias
// edge loop unrolled x4 for memory-level parallelism
__global__ __launch_bounds__(256) void k_agg(
    const float* __restrict__ w, const float* __restrict__ den,
    const int* __restrict__ row_ptr, const int* __restrict__ eids,
    const int* __restrict__ srcArr, const float* __restrict__ xl,
    const float* __restrict__ bias, float* __restrict__ xout, int N, int E) {
    int wid = (blockIdx.x * blockDim.x + threadIdx.x) >> 6;
    int lane = threadIdx.x & 63;
    if (wid >= N) return;
    int s = row_ptr[wid], e = row_ptr[wid + 1];
    float2 acc = make_float2(0.f, 0.f);
    for (int c0 = s; c0 < e; c0 += 64) {
        int m = min(64, e - c0);
        float wv = 0.f; int sv = 0;
        if (lane < m) {
            int eid = eids[c0 + lane];
            wv = w[eid];
            sv = (eid < E) ? srcArr[eid] : (eid - E);
        }
        int p = 0;
        for (; p + 4 <= m; p += 4) {
            float w0 = __shfl(wv, p),     w1 = __shfl(wv, p + 1);
            float w2 = __shfl(wv, p + 2), w3 = __shfl(wv, p + 3);
            int   r0 = __shfl(sv, p),     r1 = __shfl(sv, p + 1);
            int   r2 = __shfl(sv, p + 2), r3 = __shfl(sv, p + 3);
            float2 v0 = *reinterpret_cast<const float2*>(xl + (size_t)r0 * DD + 2 * lane);
            float2 v1 = *reinterpret_cast<const float2*>(xl + (size_t)r1 * DD + 2 * lane);
            float2 v2 = *reinterpret_cast<const float2*>(xl + (size_t)r2 * DD + 2 * lane);
            float2 v3 = *reinterpret_cast<const float2*>(xl + (size_t)r3 * DD + 2 * lane);
            acc.x += w0 * v0.x; acc.y += w0 * v0.y;
            acc.x += w1 * v1.x; acc.y += w1 * v1.y;
            acc.x += w2 * v2.x; acc.y += w2 * v2.y;
            acc.x += w3 * v3.x; acc.y += w3 * v3.y;
        }
        for (; p < m; ++p) {
            float wp = __shfl(wv, p);
            int   rw = __shfl(sv, p);
            float2 v = *reinterpret_cast<const float2*>(xl + (size_t)rw * DD + 2 * lane);
            acc.x += wp * v.x;
            acc.y += wp * v.y;
        }
    }
    float inv = 1.0f / den[wid];
    float2 bv = *reinterpret_cast<const float2*>(bias + 2 * lane);
    float2 o = make_float2(acc.x * inv + bv.x, acc.y * inv + bv.y);
    *reinterpret_cast<float2*>(xout + (size_t)wid * DD + 2 * lane) = o;
}

// ---------------- final score + top-k ----------------

__global__ __launch_bounds__(256) void k_scores(const float* __restrict__ X,
                                                const float* __restrict__ Wf,
                                                const float* __restrict__ bf,
                                                float* __restrict__ scores, int N) {
    int gid = blockIdx.x * blockDim.x + threadIdx.x;
    int node = gid >> 6;
    int lane = threadIdx.x & 63;
    if (node >= N) return;
    float2 xv = *reinterpret_cast<const float2*>(&X[(size_t)node * DD + lane * 2]);
    float2 wv = *reinterpret_cast<const float2*>(&Wf[lane * 2]);
    float p = xv.x * wv.x + xv.y * wv.y;
    p += __shfl_xor(p, 32);
    p += __shfl_xor(p, 16);
    p += __shfl_xor(p, 8);
    p += __shfl_xor(p, 4);
    p += __shfl_xor(p, 2);
    p += __shfl_xor(p, 1);
    if (lane == 0) scores[node] = p + bf[0];
}

__device__ __forceinline__ bool tk_better(float a, int ai, float b, int bi) {
    return (a > b) || (a == b && ai < bi);
}

__global__ __launch_bounds__(1024) void k_topk(const float* __restrict__ scores, int N,
                                               float* __restrict__ out) {
    __shared__ float lv[1024 * 10];
    __shared__ int li[1024 * 10];
    int t = threadIdx.x;
    float v[10]; int ix[10];
    #pragma unroll
    for (int j = 0; j < 10; ++j) { v[j] = -FLT_MAX; ix[j] = 0x7fffffff; }
    for (int i = t; i < N; i += 1024) {
        float sv = scores[i];
        if (tk_better(sv, i, v[9], ix[9])) {
            v[9] = sv; ix[9] = i;
            #pragma unroll
            for (int j = 9; j > 0; --j) {
                if (tk_better(v[j], ix[j], v[j - 1], ix[j - 1])) {
                    float tv = v[j]; v[j] = v[j - 1]; v[j - 1] = tv;
                    int ti = ix[j]; ix[j] = ix[j - 1]; ix[j - 1] = ti;
                }
            }
        }
    }
    #pragma unroll
    for (int j = 0; j < 10; ++j) { lv[t * 10 + j] = v[j]; li[t * 10 + j] = ix[j]; }
    __syncthreads();
    for (int sh = 512; sh >= 1; sh >>= 1) {
        if (t < sh) {
            float bv[10]; int bi[10];
            #pragma unroll
            for (int j = 0; j < 10; ++j) { bv[j] = lv[(t + sh) * 10 + j]; bi[j] = li[(t + sh) * 10 + j]; }
            float mv[10]; int mi[10];
            int i1 = 0, i2 = 0;
            #pragma unroll
            for (int k = 0; k < 10; ++k) {
                if (tk_better(v[i1], ix[i1], bv[i2], bi[i2])) { mv[k] = v[i1]; mi[k] = ix[i1]; ++i1; }
                else { mv[k] = bv[i2]; mi[k] = bi[i2]; ++i2; }
            }
            #pragma unroll
            for (int j = 0; j < 10; ++j) {
                v[j] = mv[j]; ix[j] = mi[j];
                lv[t * 10 + j] = v[j]; li[t * 10 + j] = ix[j];
            }
        }
        __syncthreads();
    }
    if (t == 0) {
        #pragma unroll
        for (int j = 0; j < 10; ++j) {
            out[j] = v[j];
            out[10 + j] = (float)ix[j];
        }
    }
}

// ---------------- host launch ----------------

static inline size_t alignup(size_t v) { return (v + 255) & ~(size_t)255; }

extern "C" void kernel_launch(void* const* d_in, const int* in_sizes, int n_in,
                              void* d_out, int out_size, void* d_ws, size_t ws_size,
                              hipStream_t stream) {
    const float* x    = (const float*)d_in[0];
    const int*   ei   = (const int*)d_in[1];
    const float* ea   = (const float*)d_in[2];
    const float* Wl   = (const float*)d_in[3];
    const float* bl   = (const float*)d_in[4];
    const float* Wr   = (const float*)d_in[5];
    const float* br   = (const float*)d_in[6];
    const float* We   = (const float*)d_in[7];
    const float* att  = (const float*)d_in[8];
    const float* bias = (const float*)d_in[9];
    const float* Wf   = (const float*)d_in[10];
    const float* bf   = (const float*)d_in[11];

    int N = in_sizes[0] / DD;
    int E = in_sizes[1] / 2;
    int L = in_sizes[3] / (DD * DD);
    int Etot = E + N;
    const int* src = ei;
    const int* dst = ei + E;

    size_t off = 0;
    char* wsb = (char*)d_ws;
    auto carve = [&](size_t bytes) -> void* { void* p = wsb + off; off += alignup(bytes); return p; };
    unsigned short* WAe = (unsigned short*)carve((size_t)L * 32768 * 2);
    unsigned short* WAl = (unsigned short*)carve((size_t)L * 32768 * 2);
    unsigned short* WAr = (unsigned short*)carve((size_t)L * 32768 * 2);
    int*   cnt       = (int*)carve((size_t)N * 4);
    int*   fill      = (int*)carve((size_t)N * 4);
    int*   row_ptr   = (int*)carve((size_t)(N + 1) * 4);
    int*   eids      = (int*)carve((size_t)Etot * 4);
    float* logits    = (float*)carve((size_t)Etot * 4);
    float* denBuf    = (float*)carve((size_t)N * 4);
    float* loop_attr = (float*)carve((size_t)N * DD * 4);
    float* xl        = (float*)carve((size_t)N * DD * 4);
    float* xr        = (float*)carve((size_t)N * DD * 4);
    float* xa        = (float*)carve((size_t)N * DD * 4);
    float* xb        = (float*)carve((size_t)N * DD * 4);
    float* scoresBuf = (float*)carve((size_t)N * 4);
    (void)ws_size; (void)n_in; (void)out_size;

    hipMemsetAsync(cnt, 0, (size_t)N * 4, stream);
    hipMemsetAsync(fill, 0, (size_t)N * 4, stream);

    int ppBlocks = (L * DD * DD + 255) / 256;
    k_prepack<<<ppBlocks, 256, 0, stream>>>(We, WAe, L);
    k_prepack<<<ppBlocks, 256, 0, stream>>>(Wl, WAl, L);
    k_prepack<<<ppBlocks, 256, 0, stream>>>(Wr, WAr, L);
    k_hist<<<(E + 255) / 256, 256, 0, stream>>>(dst, E, cnt);
    k_scan<<<1, 1024, 0, stream>>>(cnt, row_ptr, N);
    k_scatter<<<(Etot + 255) / 256, 256, 0, stream>>>(dst, E, N, row_ptr, fill, cnt, eids);
    k_sort_rows<<<(N + 255) / 256, 256, 0, stream>>>(row_ptr, eids, N);
    int waveBlocks = (N * 64 + 255) / 256;
    k_loop_attr<<<waveBlocks, 256, 0, stream>>>(ea, row_ptr, cnt, eids, loop_attr, N);

    const float* xin = x;
    float* xout = xa;
    int gemmBlocks = (N + 63) / 64;
    int edgeBlocks = (Etot + 63) / 64;
    for (int l = 0; l < L; ++l) {
        k_gemm_mfma<<<gemmBlocks, 256, 0, stream>>>(xin, WAl + (size_t)l * 32768, bl + (size_t)l * DD, xl, N);
        k_gemm_mfma<<<gemmBlocks, 256, 0, stream>>>(xin, WAr + (size_t)l * 32768, br + (size_t)l * DD, xr, N);
        k_edge_mfma<<<edgeBlocks, 256, 0, stream>>>(ea, loop_attr, src, dst,
                                                    WAe + (size_t)l * 32768, att + (size_t)l * DD,
                                                    xl, xr, logits, E, Etot);
        k_softmax<<<(N + 255) / 256, 256, 0, stream>>>(logits, row_ptr, eids, denBuf, N);
        k_agg<<<waveBlocks, 256, 0, stream>>>(logits, denBuf, row_ptr, eids, src, xl,
                                              bias + (size_t)l * DD, xout, N, E);
        xin = xout;
        xout = (xout == xa) ? xb : xa;
    }
    k_scores<<<(N + 3) / 4, 256, 0, stream>>>(xin, Wf, bf, scoresBuf, N);
    k_topk<<<1, 1024, 0, stream>>>(scoresBuf, N, (float*)d_out);
}

// Round 7
// 1205.024 us; speedup vs baseline: 1.2507x; 1.2405x over previous
//
#include <hip/hip_runtime.h>
#include <hip/hip_bf16.h>
#include <float.h>

#define DD 128
#define NEG_SLOPE 0.2f

typedef __attribute__((ext_vector_type(8))) short bf16x8;
typedef __attribute__((ext_vector_type(4))) float f32x4;

__device__ __forceinline__ float lrelu(float v) {
    return fmaxf(v, 0.0f) + NEG_SLOPE * fminf(v, 0.0f);
}

__device__ __forceinline__ unsigned short f2bf(float f) {
    unsigned u = __float_as_uint(f);
    u += 0x7fff + ((u >> 16) & 1);   // round-to-nearest-even
    return (unsigned short)(u >> 16);
}
__device__ __forceinline__ float bf2f(unsigned short h) {
    return __uint_as_float(((unsigned)h) << 16);
}

// ---------------- preprocessing ----------------

__global__ void k_hist(const int* __restrict__ dst, int E, int* __restrict__ cnt) {
    int i = blockIdx.x * blockDim.x + threadIdx.x;
    if (i < E) atomicAdd(&cnt[dst[i]], 1);
}

__global__ __launch_bounds__(1024) void k_scan(const int* __restrict__ cnt,
                                               int* __restrict__ row_ptr, int N) {
    __shared__ int sums[1024];
    int tid = threadIdx.x;
    int total = N + 1;
    int chunk = (total + 1023) / 1024;
    int lo = tid * chunk;
    int hi = min(lo + chunk, total);
    int s = 0;
    for (int i = lo; i < hi; ++i) s += (i < N) ? (cnt[i] + 1) : 0;
    sums[tid] = s;
    __syncthreads();
    for (int off = 1; off < 1024; off <<= 1) {
        int t = (tid >= off) ? sums[tid - off] : 0;
        __syncthreads();
        sums[tid] += t;
        __syncthreads();
    }
    int run = sums[tid] - s;
    for (int i = lo; i < hi; ++i) {
        row_ptr[i] = run;
        run += (i < N) ? (cnt[i] + 1) : 0;
    }
}

__global__ void k_scatter(const int* __restrict__ dst, int E, int N,
                          const int* __restrict__ row_ptr, int* __restrict__ fill,
                          const int* __restrict__ cnt, int* __restrict__ eids) {
    int i = blockIdx.x * blockDim.x + threadIdx.x;
    int tot = E + N;
    if (i >= tot) return;
    if (i < E) {
        int d = dst[i];
        int p = atomicAdd(&fill[d], 1);
        eids[row_ptr[d] + p] = i;
    } else {
        int n = i - E;
        eids[row_ptr[n] + cnt[n]] = E + n;
    }
}

// canonicalize row order (atomic scatter order varies per launch)
__global__ void k_sort_rows(const int* __restrict__ row_ptr, int* __restrict__ eids, int N) {
    int n = blockIdx.x * blockDim.x + threadIdx.x;
    if (n >= N) return;
    int s = row_ptr[n], e = row_ptr[n + 1];
    for (int i = s + 1; i < e; ++i) {
        int v = eids[i];
        int j = i - 1;
        while (j >= s && eids[j] > v) { eids[j + 1] = eids[j]; --j; }
        eids[j + 1] = v;
    }
}

// pos[eid] = CSR slot of edge eid; csr_src[p] = source node of the edge in slot p
__global__ void k_invert(const int* __restrict__ eids, const int* __restrict__ srcArr,
                         int* __restrict__ pos, int* __restrict__ csr_src, int Etot, int E) {
    int p = blockIdx.x * blockDim.x + threadIdx.x;
    if (p >= Etot) return;
    int eid = eids[p];
    pos[eid] = p;
    csr_src[p] = (eid < E) ? srcArr[eid] : (eid - E);
}

// wave-per-node: loop_attr[n,:] = mean of incoming edge attrs (0 if none)
__global__ __launch_bounds__(256) void k_loop_attr(const float* __restrict__ ea,
                                                   const int* __restrict__ row_ptr,
                                                   const int* __restrict__ cnt,
                                                   const int* __restrict__ eids,
                                                   float* __restrict__ loop_attr, int N) {
    int wid = (blockIdx.x * blockDim.x + threadIdx.x) >> 6;
    int lane = threadIdx.x & 63;
    if (wid >= N) return;
    int s = row_ptr[wid];
    int c = cnt[wid];
    float2 acc = make_float2(0.f, 0.f);
    for (int c0 = 0; c0 < c; c0 += 64) {
        int m = min(64, c - c0);
        int eid = 0;
        if (lane < m) eid = eids[s + c0 + lane];
        int p = 0;
        for (; p + 4 <= m; p += 4) {
            int e0 = __shfl(eid, p), e1 = __shfl(eid, p + 1);
            int e2 = __shfl(eid, p + 2), e3 = __shfl(eid, p + 3);
            float2 v0 = *reinterpret_cast<const float2*>(ea + (size_t)e0 * DD + 2 * lane);
            float2 v1 = *reinterpret_cast<const float2*>(ea + (size_t)e1 * DD + 2 * lane);
            float2 v2 = *reinterpret_cast<const float2*>(ea + (size_t)e2 * DD + 2 * lane);
            float2 v3 = *reinterpret_cast<const float2*>(ea + (size_t)e3 * DD + 2 * lane);
            acc.x += v0.x; acc.y += v0.y;
            acc.x += v1.x; acc.y += v1.y;
            acc.x += v2.x; acc.y += v2.y;
            acc.x += v3.x; acc.y += v3.y;
        }
        for (; p < m; ++p) {
            int e = __shfl(eid, p);
            float2 v = *reinterpret_cast<const float2*>(ea + (size_t)e * DD + 2 * lane);
            acc.x += v.x; acc.y += v.y;
        }
    }
    float inv = 1.0f / fmaxf((float)c, 1.0f);
    float2 o = make_float2(acc.x * inv, acc.y * inv);
    *reinterpret_cast<float2*>(loop_attr + (size_t)wid * DD + 2 * lane) = o;
}

// prepack W (per layer) into MFMA A-fragment order, bf16 hi/lo.
// WA[l][h][ks][g][j][i] = bf16_h( W[l][ks*32+g*8+i][j] ),  j=0..127, i=0..7
__global__ void k_prepack(const float* __restrict__ W, unsigned short* __restrict__ WA, int L) {
    int idx = blockIdx.x * blockDim.x + threadIdx.x;
    int total = L * DD * DD;
    if (idx >= total) return;
    int l = idx >> 14;
    int rem = idx & 16383;
    int k = rem >> 7;
    int j = rem & 127;
    float w = W[(size_t)l * 16384 + (size_t)k * DD + j];
    unsigned short h = f2bf(w);
    unsigned short lo = f2bf(w - bf2f(h));
    int ks = k >> 5, g = (k >> 3) & 3, i = k & 7;
    size_t off = ((size_t)(ks * 4 + g) * DD + j) * 8 + i;   // within half
    unsigned short* base = WA + (size_t)l * 32768;
    base[off] = h;
    base[16384 + off] = lo;
}

// ---------------- per-layer kernels ----------------

// MFMA node transform: Y[r,:] = X[r,:] @ W + b   (bf16x2 split, 3 products)
// 8 waves x 32 rows = 256 rows/block; weights (hi+lo, 64KB) staged in LDS.
__global__ __launch_bounds__(512, 2) void k_gemm_mfma(
    const float* __restrict__ X, const unsigned short* __restrict__ WA,
    const float* __restrict__ b, float* __restrict__ Y, int N) {

    __shared__ unsigned short WAs[32768];
    {
        const uint4* gsrc = reinterpret_cast<const uint4*>(WA);
        uint4* ldst = reinterpret_cast<uint4*>(WAs);
        int t = threadIdx.x;
        #pragma unroll
        for (int i = 0; i < 8; ++i) ldst[t + i * 512] = gsrc[t + i * 512];
    }
    __syncthreads();

    int tid  = threadIdx.x;
    int lane = tid & 63;
    int wv   = tid >> 6;
    int lc   = lane & 15;
    int g    = lane >> 4;

    int r0 = blockIdx.x * 256 + wv * 32;
    int rv[2]; bool ok[2];
    const float* rp[2];
    #pragma unroll
    for (int nf = 0; nf < 2; ++nf) {
        rv[nf] = r0 + nf * 16 + lc;
        ok[nf] = (rv[nf] < N);
        rp[nf] = X + (size_t)(ok[nf] ? rv[nf] : 0) * DD;
    }

    f32x4 acc[8][2];
    #pragma unroll
    for (int m = 0; m < 8; ++m)
        #pragma unroll
        for (int n = 0; n < 2; ++n)
            acc[m][n] = (f32x4){0.f, 0.f, 0.f, 0.f};

    float4 pr0[2], pr1[2];
    #pragma unroll
    for (int nf = 0; nf < 2; ++nf) {
        pr0[nf] = *reinterpret_cast<const float4*>(rp[nf] + g * 8);
        pr1[nf] = *reinterpret_cast<const float4*>(rp[nf] + g * 8 + 4);
    }

    #pragma unroll
    for (int ks = 0; ks < 4; ++ks) {
        bf16x8 Bh[2], Bl[2];
        #pragma unroll
        for (int nf = 0; nf < 2; ++nf) {
            float v[8] = {pr0[nf].x, pr0[nf].y, pr0[nf].z, pr0[nf].w,
                          pr1[nf].x, pr1[nf].y, pr1[nf].z, pr1[nf].w};
            #pragma unroll
            for (int i = 0; i < 8; ++i) {
                unsigned short h = f2bf(v[i]);
                Bh[nf][i] = (short)h;
                Bl[nf][i] = (short)f2bf(v[i] - bf2f(h));
            }
        }
        if (ks < 3) {
            int k0n = (ks + 1) * 32 + g * 8;
            #pragma unroll
            for (int nf = 0; nf < 2; ++nf) {
                pr0[nf] = *reinterpret_cast<const float4*>(rp[nf] + k0n);
                pr1[nf] = *reinterpret_cast<const float4*>(rp[nf] + k0n + 4);
            }
        }
        #pragma unroll
        for (int mf = 0; mf < 8; ++mf) {
            int aoff = ((ks * 4 + g) * DD + (mf * 16 + lc)) * 8;
            bf16x8 Ah = *reinterpret_cast<const bf16x8*>(&WAs[aoff]);
            bf16x8 Al = *reinterpret_cast<const bf16x8*>(&WAs[16384 + aoff]);
            #pragma unroll
            for (int nf = 0; nf < 2; ++nf) {
                acc[mf][nf] = __builtin_amdgcn_mfma_f32_16x16x32_bf16(Ah, Bh[nf], acc[mf][nf], 0, 0, 0);
                acc[mf][nf] = __builtin_amdgcn_mfma_f32_16x16x32_bf16(Al, Bh[nf], acc[mf][nf], 0, 0, 0);
                acc[mf][nf] = __builtin_amdgcn_mfma_f32_16x16x32_bf16(Ah, Bl[nf], acc[mf][nf], 0, 0, 0);
            }
        }
    }

    #pragma unroll
    for (int mf = 0; mf < 8; ++mf) {
        int f0 = mf * 16 + g * 4;
        float4 bv = *reinterpret_cast<const float4*>(b + f0);
        #pragma unroll
        for (int nf = 0; nf < 2; ++nf) {
            if (!ok[nf]) continue;
            float4 o;
            o.x = acc[mf][nf][0] + bv.x;
            o.y = acc[mf][nf][1] + bv.y;
            o.z = acc[mf][nf][2] + bv.z;
            o.w = acc[mf][nf][3] + bv.w;
            *reinterpret_cast<float4*>(Y + (size_t)rv[nf] * DD + f0) = o;
        }
    }
}

// MFMA edge-logits: D[j][e] = sum_k We[k][j]*ea[e][k]  (bf16x2 split, 3 products)
// 8 waves x 32 edges = 256 edges/block; weights staged in LDS. Writes CSR-slot logits.
__global__ __launch_bounds__(512, 2) void k_edge_mfma(
    const float* __restrict__ ea, const float* __restrict__ loop_attr,
    const int* __restrict__ srcArr, const int* __restrict__ dstArr,
    const unsigned short* __restrict__ WA, const float* __restrict__ att,
    const float* __restrict__ xl, const float* __restrict__ xr,
    const int* __restrict__ pos, float* __restrict__ wlog, int E, int Etot) {

    __shared__ unsigned short WAs[32768];
    {
        const uint4* gsrc = reinterpret_cast<const uint4*>(WA);
        uint4* ldst = reinterpret_cast<uint4*>(WAs);
        int t = threadIdx.x;
        #pragma unroll
        for (int i = 0; i < 8; ++i) ldst[t + i * 512] = gsrc[t + i * 512];
    }
    __syncthreads();

    int tid  = threadIdx.x;
    int lane = tid & 63;
    int wv   = tid >> 6;
    int lc   = lane & 15;
    int g    = lane >> 4;

    int e0 = blockIdx.x * 256 + wv * 32;

    const float* rp[2];
    int ev[2]; bool ok[2];
    #pragma unroll
    for (int nf = 0; nf < 2; ++nf) {
        int e = e0 + nf * 16 + lc;
        ev[nf] = e;
        ok[nf] = (e < Etot);
        if (e < E)         rp[nf] = ea + (size_t)e * DD;
        else if (e < Etot) rp[nf] = loop_attr + (size_t)(e - E) * DD;
        else               rp[nf] = ea;
    }

    f32x4 acc[8][2];
    #pragma unroll
    for (int m = 0; m < 8; ++m)
        #pragma unroll
        for (int n = 0; n < 2; ++n)
            acc[m][n] = (f32x4){0.f, 0.f, 0.f, 0.f};

    float4 pr0[2], pr1[2];
    #pragma unroll
    for (int nf = 0; nf < 2; ++nf) {
        pr0[nf] = *reinterpret_cast<const float4*>(rp[nf] + g * 8);
        pr1[nf] = *reinterpret_cast<const float4*>(rp[nf] + g * 8 + 4);
    }

    #pragma unroll
    for (int ks = 0; ks < 4; ++ks) {
        bf16x8 Bh[2], Bl[2];
        #pragma unroll
        for (int nf = 0; nf < 2; ++nf) {
            float v[8] = {pr0[nf].x, pr0[nf].y, pr0[nf].z, pr0[nf].w,
                          pr1[nf].x, pr1[nf].y, pr1[nf].z, pr1[nf].w};
            #pragma unroll
            for (int i = 0; i < 8; ++i) {
                unsigned short h = f2bf(v[i]);
                Bh[nf][i] = (short)h;
                Bl[nf][i] = (short)f2bf(v[i] - bf2f(h));
            }
        }
        if (ks < 3) {
            int k0n = (ks + 1) * 32 + g * 8;
            #pragma unroll
            for (int nf = 0; nf < 2; ++nf) {
                pr0[nf] = *reinterpret_cast<const float4*>(rp[nf] + k0n);
                pr1[nf] = *reinterpret_cast<const float4*>(rp[nf] + k0n + 4);
            }
        }
        #pragma unroll
        for (int mf = 0; mf < 8; ++mf) {
            int aoff = ((ks * 4 + g) * DD + (mf * 16 + lc)) * 8;
            bf16x8 Ah = *reinterpret_cast<const bf16x8*>(&WAs[aoff]);
            bf16x8 Al = *reinterpret_cast<const bf16x8*>(&WAs[16384 + aoff]);
            #pragma unroll
            for (int nf = 0; nf < 2; ++nf) {
                acc[mf][nf] = __builtin_amdgcn_mfma_f32_16x16x32_bf16(Ah, Bh[nf], acc[mf][nf], 0, 0, 0);
                acc[mf][nf] = __builtin_amdgcn_mfma_f32_16x16x32_bf16(Al, Bh[nf], acc[mf][nf], 0, 0, 0);
                acc[mf][nf] = __builtin_amdgcn_mfma_f32_16x16x32_bf16(Ah, Bl[nf], acc[mf][nf], 0, 0, 0);
            }
        }
    }

    // epilogue: per acc reg r, feature f = mf*16 + g*4 + r; edge = ev[nf]
    int sn[2], dn[2];
    #pragma unroll
    for (int nf = 0; nf < 2; ++nf) {
        int e = ev[nf];
        if (e < E)       { sn[nf] = srcArr[e]; dn[nf] = dstArr[e]; }
        else if (ok[nf]) { sn[nf] = e - E; dn[nf] = e - E; }
        else             { sn[nf] = 0; dn[nf] = 0; }
    }
    float partial[2] = {0.f, 0.f};
    #pragma unroll
    for (int mf = 0; mf < 8; ++mf) {
        int f0 = mf * 16 + g * 4;
        float4 attv = *reinterpret_cast<const float4*>(att + f0);
        #pragma unroll
        for (int nf = 0; nf < 2; ++nf) {
            float4 xlv = *reinterpret_cast<const float4*>(xl + (size_t)sn[nf] * DD + f0);
            float4 xrv = *reinterpret_cast<const float4*>(xr + (size_t)dn[nf] * DD + f0);
            float t0 = acc[mf][nf][0] + xlv.x + xrv.x;
            float t1 = acc[mf][nf][1] + xlv.y + xrv.y;
            float t2 = acc[mf][nf][2] + xlv.z + xrv.z;
            float t3 = acc[mf][nf][3] + xlv.w + xrv.w;
            partial[nf] += attv.x * lrelu(t0) + attv.y * lrelu(t1)
                         + attv.z * lrelu(t2) + attv.w * lrelu(t3);
        }
    }
    #pragma unroll
    for (int nf = 0; nf < 2; ++nf) {
        float p = partial[nf];
        p += __shfl_xor(p, 16);
        p += __shfl_xor(p, 32);
        if (lane < 16 && ok[nf]) wlog[pos[ev[nf]]] = p;
    }
}

// fused softmax + aggregation, wave per node, CSR-contiguous weights/srcs.
// out[n,:] = (sum_p exp(w[p]-mx)*xl[csr_src[p],:]) / den + bias
__global__ __launch_bounds__(256) void k_sfx_agg(
    const float* __restrict__ wlog, const int* __restrict__ row_ptr,
    const int* __restrict__ csr_src, const float* __restrict__ xl,
    const float* __restrict__ bias, float* __restrict__ xout, int N) {
    int wid = (blockIdx.x * blockDim.x + threadIdx.x) >> 6;
    int lane = threadIdx.x & 63;
    if (wid >= N) return;
    int s = row_ptr[wid], e = row_ptr[wid + 1];
    // max (butterfly, deterministic)
    float mx = -FLT_MAX;
    for (int c0 = s; c0 < e; c0 += 64) {
        float l = (c0 + lane < e) ? wlog[c0 + lane] : -FLT_MAX;
        l = fmaxf(l, __shfl_xor(l, 32));
        l = fmaxf(l, __shfl_xor(l, 16));
        l = fmaxf(l, __shfl_xor(l, 8));
        l = fmaxf(l, __shfl_xor(l, 4));
        l = fmaxf(l, __shfl_xor(l, 2));
        l = fmaxf(l, __shfl_xor(l, 1));
        mx = fmaxf(mx, l);
    }
    // denominator
    float den = 0.f;
    for (int c0 = s; c0 < e; c0 += 64) {
        float w = (c0 + lane < e) ? __expf(wlog[c0 + lane] - mx) : 0.f;
        w += __shfl_xor(w, 32);
        w += __shfl_xor(w, 16);
        w += __shfl_xor(w, 8);
        w += __shfl_xor(w, 4);
        w += __shfl_xor(w, 2);
        w += __shfl_xor(w, 1);
        den += w;
    }
    float inv = 1.0f / den;
    // aggregate
    float2 acc = make_float2(0.f, 0.f);
    for (int c0 = s; c0 < e; c0 += 64) {
        int m = min(64, e - c0);
        float av = 0.f; int sv = 0;
        if (lane < m) {
            av = __expf(wlog[c0 + lane] - mx) * inv;
            sv = csr_src[c0 + lane];
        }
        int p = 0;
        for (; p + 4 <= m; p += 4) {
            float a0 = __shfl(av, p),     a1 = __shfl(av, p + 1);
            float a2 = __shfl(av, p + 2), a3 = __shfl(av, p + 3);
            int   r0 = __shfl(sv, p),     r1 = __shfl(sv, p + 1);
            int   r2 = __shfl(sv, p + 2), r3 = __shfl(sv, p + 3);
            float2 v0 = *reinterpret_cast<const float2*>(xl + (size_t)r0 * DD + 2 * lane);
            float2 v1 = *reinterpret_cast<const float2*>(xl + (size_t)r1 * DD + 2 * lane);
            float2 v2 = *reinterpret_cast<const float2*>(xl + (size_t)r2 * DD + 2 * lane);
            float2 v3 = *reinterpret_cast<const float2*>(xl + (size_t)r3 * DD + 2 * lane);
            acc.x += a0 * v0.x; acc.y += a0 * v0.y;
            acc.x += a1 * v1.x; acc.y += a1 * v1.y;
            acc.x += a2 * v2.x; acc.y += a2 * v2.y;
            acc.x += a3 * v3.x; acc.y += a3 * v3.y;
        }
        for (; p < m; ++p) {
            float ap = __shfl(av, p);
            int   rw = __shfl(sv, p);
            float2 v = *reinterpret_cast<const float2*>(xl + (size_t)rw * DD + 2 * lane);
            acc.x += ap * v.x;
            acc.y += ap * v.y;
        }
    }
    float2 bv = *reinterpret_cast<const float2*>(bias + 2 * lane);
    float2 o = make_float2(acc.x + bv.x, acc.y + bv.y);
    *reinterpret_cast<float2*>(xout + (size_t)wid * DD + 2 * lane) = o;
}

// ---------------- final score + top-k ----------------

__global__ __launch_bounds__(256) void k_scores(const float* __restrict__ X,
                                                const float* __restrict__ Wf,
                                                const float* __restrict__ bf,
                                                float* __restrict__ scores, int N) {
    int gid = blockIdx.x * blockDim.x + threadIdx.x;
    int node = gid >> 6;
    int lane = threadIdx.x & 63;
    if (node >= N) return;
    float2 xv = *reinterpret_cast<const float2*>(&X[(size_t)node * DD + lane * 2]);
    float2 wv = *reinterpret_cast<const float2*>(&Wf[lane * 2]);
    float p = xv.x * wv.x + xv.y * wv.y;
    p += __shfl_xor(p, 32);
    p += __shfl_xor(p, 16);
    p += __shfl_xor(p, 8);
    p += __shfl_xor(p, 4);
    p += __shfl_xor(p, 2);
    p += __shfl_xor(p, 1);
    if (lane == 0) scores[node] = p + bf[0];
}

__device__ __forceinline__ bool tk_better(float a, int ai, float b, int bi) {
    return (a > b) || (a == b && ai < bi);
}

__global__ __launch_bounds__(1024) void k_topk(const float* __restrict__ scores, int N,
                                               float* __restrict__ out) {
    __shared__ float lv[1024 * 10];
    __shared__ int li[1024 * 10];
    int t = threadIdx.x;
    float v[10]; int ix[10];
    #pragma unroll
    for (int j = 0; j < 10; ++j) { v[j] = -FLT_MAX; ix[j] = 0x7fffffff; }
    for (int i = t; i < N; i += 1024) {
        float sv = scores[i];
        if (tk_better(sv, i, v[9], ix[9])) {
            v[9] = sv; ix[9] = i;
            #pragma unroll
            for (int j = 9; j > 0; --j) {
                if (tk_better(v[j], ix[j], v[j - 1], ix[j - 1])) {
                    float tv = v[j]; v[j] = v[j - 1]; v[j - 1] = tv;
                    int ti = ix[j]; ix[j] = ix[j - 1]; ix[j - 1] = ti;
                }
            }
        }
    }
    #pragma unroll
    for (int j = 0; j < 10; ++j) { lv[t * 10 + j] = v[j]; li[t * 10 + j] = ix[j]; }
    __syncthreads();
    for (int sh = 512; sh >= 1; sh >>= 1) {
        if (t < sh) {
            float bv[10]; int bi[10];
            #pragma unroll
            for (int j = 0; j < 10; ++j) { bv[j] = lv[(t + sh) * 10 + j]; bi[j] = li[(t + sh) * 10 + j]; }
            float mv[10]; int mi[10];
            int i1 = 0, i2 = 0;
            #pragma unroll
            for (int k = 0; k < 10; ++k) {
                if (tk_better(v[i1], ix[i1], bv[i2], bi[i2])) { mv[k] = v[i1]; mi[k] = ix[i1]; ++i1; }
                else { mv[k] = bv[i2]; mi[k] = bi[i2]; ++i2; }
            }
            #pragma unroll
            for (int j = 0; j < 10; ++j) {
                v[j] = mv[j]; ix[j] = mi[j];
                lv[t * 10 + j] = v[j]; li[t * 10 + j] = ix[j];
            }
        }
        __syncthreads();
    }
    if (t == 0) {
        #pragma unroll
        for (int j = 0; j < 10; ++j) {
            out[j] = v[j];
            out[10 + j] = (float)ix[j];
        }
    }
}

// ---------------- host launch ----------------

static inline size_t alignup(size_t v) { return (v + 255) & ~(size_t)255; }

extern "C" void kernel_launch(void* const* d_in, const int* in_sizes, int n_in,
                              void* d_out, int out_size, void* d_ws, size_t ws_size,
                              hipStream_t stream) {
    const float* x    = (const float*)d_in[0];
    const int*   ei   = (const int*)d_in[1];
    const float* ea   = (const float*)d_in[2];
    const float* Wl   = (const float*)d_in[3];
    const float* bl   = (const float*)d_in[4];
    const float* Wr   = (const float*)d_in[5];
    const float* br   = (const float*)d_in[6];
    const float* We   = (const float*)d_in[7];
    const float* att  = (const float*)d_in[8];
    const float* bias = (const float*)d_in[9];
    const float* Wf   = (const float*)d_in[10];
    const float* bf   = (const float*)d_in[11];

    int N = in_sizes[0] / DD;
    int E = in_sizes[1] / 2;
    int L = in_sizes[3] / (DD * DD);
    int Etot = E + N;
    const int* src = ei;
    const int* dst = ei + E;

    size_t off = 0;
    char* wsb = (char*)d_ws;
    auto carve = [&](size_t bytes) -> void* { void* p = wsb + off; off += alignup(bytes); return p; };
    unsigned short* WAe = (unsigned short*)carve((size_t)L * 32768 * 2);
    unsigned short* WAl = (unsigned short*)carve((size_t)L * 32768 * 2);
    unsigned short* WAr = (unsigned short*)carve((size_t)L * 32768 * 2);
    int*   cnt       = (int*)carve((size_t)N * 4);
    int*   fill      = (int*)carve((size_t)N * 4);
    int*   row_ptr   = (int*)carve((size_t)(N + 1) * 4);
    int*   eids      = (int*)carve((size_t)Etot * 4);
    int*   pos       = (int*)carve((size_t)Etot * 4);
    int*   csr_src   = (int*)carve((size_t)Etot * 4);
    float* wlog      = (float*)carve((size_t)Etot * 4);
    float* loop_attr = (float*)carve((size_t)N * DD * 4);
    float* xl        = (float*)carve((size_t)N * DD * 4);
    float* xr        = (float*)carve((size_t)N * DD * 4);
    float* xa        = (float*)carve((size_t)N * DD * 4);
    float* xb        = (float*)carve((size_t)N * DD * 4);
    float* scoresBuf = (float*)carve((size_t)N * 4);
    (void)ws_size; (void)n_in; (void)out_size;

    hipMemsetAsync(cnt, 0, (size_t)N * 4, stream);
    hipMemsetAsync(fill, 0, (size_t)N * 4, stream);

    int ppBlocks = (L * DD * DD + 255) / 256;
    k_prepack<<<ppBlocks, 256, 0, stream>>>(We, WAe, L);
    k_prepack<<<ppBlocks, 256, 0, stream>>>(Wl, WAl, L);
    k_prepack<<<ppBlocks, 256, 0, stream>>>(Wr, WAr, L);
    k_hist<<<(E + 255) / 256, 256, 0, stream>>>(dst, E, cnt);
    k_scan<<<1, 1024, 0, stream>>>(cnt, row_ptr, N);
    k_scatter<<<(Etot + 255) / 256, 256, 0, stream>>>(dst, E, N, row_ptr, fill, cnt, eids);
    k_sort_rows<<<(N + 255) / 256, 256, 0, stream>>>(row_ptr, eids, N);
    k_invert<<<(Etot + 255) / 256, 256, 0, stream>>>(eids, src, pos, csr_src, Etot, E);
    int waveBlocks = (N * 64 + 255) / 256;
    k_loop_attr<<<waveBlocks, 256, 0, stream>>>(ea, row_ptr, cnt, eids, loop_attr, N);

    const float* xin = x;
    float* xout = xa;
    int gemmBlocks = (N + 255) / 256;
    int edgeBlocks = (Etot + 255) / 256;
    for (int l = 0; l < L; ++l) {
        k_gemm_mfma<<<gemmBlocks, 512, 0, stream>>>(xin, WAl + (size_t)l * 32768, bl + (size_t)l * DD, xl, N);
        k_gemm_mfma<<<gemmBlocks, 512, 0, stream>>>(xin, WAr + (size_t)l * 32768, br + (size_t)l * DD, xr, N);
        k_edge_mfma<<<edgeBlocks, 512, 0, stream>>>(ea, loop_attr, src, dst,
                                                    WAe + (size_t)l * 32768, att + (size_t)l * DD,
                                                    xl, xr, pos, wlog, E, Etot);
        k_sfx_agg<<<waveBlocks, 256, 0, stream>>>(wlog, row_ptr, csr_src, xl,
                                                  bias + (size_t)l * DD, xout, N);
        xin = xout;
        xout = (xout == xa) ? xb : xa;
    }
    k_scores<<<(N + 3) / 4, 256, 0, stream>>>(xin, Wf, bf, scoresBuf, N);
    k_topk<<<1, 1024, 0, stream>>>(scoresBuf, N, (float*)d_out);
}